// Round 3
// baseline (1534.563 us; speedup 1.0000x reference)
//
#include <hip/hip_runtime.h>
#include <hip/hip_bf16.h>

#define B_  1024
#define L_  64
#define E_  1024
#define DC_ 768
#define N_  16384

// ---------------- ws layout (bytes) ----------------
// X    : 0          (B*DC*4   = 3,145,728)
// clue : 3145728    (B*DC*4   = 3,145,728)
// P    : 6291456    (B*N*2    = 33,554,432)  bf16 exp(-cos)
// rX   : 39845888   (B*4)
// rW   : 39849984   (N*4)
// Z    : 39915520   (B*4)
// vl   : 39919616   (B*4)
// flag : 39923712   (4)
// total ~40 MB

// ---- mask layout detection: 1 = int32 0/1, 2 = float32 0/1, 0 = bytes ----
__global__ void detect_mask(const unsigned int* __restrict__ mi, int* __restrict__ flag) {
    __shared__ int notInt, notFlt;
    if (threadIdx.x == 0) { notInt = 0; notFlt = 0; }
    __syncthreads();
    int ni = 0, nf = 0;
    for (int i = threadIdx.x; i < 16384; i += 256) {
        unsigned v = mi[i];
        if (v > 1u) ni = 1;
        if (v != 0u && v != 0x3f800000u) nf = 1;
    }
    if (ni) notInt = 1;
    if (nf) notFlt = 1;
    __syncthreads();
    if (threadIdx.x == 0) *flag = (!notInt) ? 1 : ((!notFlt) ? 2 : 0);
}

__global__ void compute_vl(const void* __restrict__ mask, const int* __restrict__ flag,
                           int* __restrict__ vl) {
    int b = blockIdx.x * blockDim.x + threadIdx.x;
    if (b >= B_) return;
    int f = *flag;
    int s = 0;
    if (f == 1) {
        const int* m = (const int*)mask;
        for (int j = 0; j < L_; ++j) s += m[b * L_ + j];
    } else if (f == 2) {
        const float* m = (const float*)mask;
        for (int j = 0; j < L_; ++j) s += (m[b * L_ + j] != 0.0f) ? 1 : 0;
    } else {
        const unsigned char* m = (const unsigned char*)mask;
        for (int j = 0; j < L_; ++j) s += m[b * L_ + j];
    }
    vl[b] = L_ - s;
}

// ---- per-row inverse L2 norm: r[row] = 1/max(||M[row]||, 1e-8) ----
__global__ __launch_bounds__(256) void rownorm(const float* __restrict__ M,
                                               float* __restrict__ r, int cols) {
    int row = blockIdx.x;
    const float* p = M + (size_t)row * cols;
    float s = 0.0f;
    for (int c = threadIdx.x; c < cols; c += 256) { float v = p[c]; s += v * v; }
    for (int off = 32; off > 0; off >>= 1) s += __shfl_down(s, off);
    __shared__ float sm[4];
    if ((threadIdx.x & 63) == 0) sm[threadIdx.x >> 6] = s;
    __syncthreads();
    if (threadIdx.x == 0) {
        float t = sm[0] + sm[1] + sm[2] + sm[3];
        float n = fmaxf(sqrtf(t), 1e-8f);
        r[row] = 1.0f / n;
    }
}

// ---- proj GEMM (NT): C[m][n] = sum_k A[m][k]*W[n][k] + bias[n] ----
// M=1024, N=768, K=1024. 64x64 tile, 4x4 per thread.
__global__ __launch_bounds__(256) void proj_gemm(const float* __restrict__ A,
                                                 const float* __restrict__ W,
                                                 const float* __restrict__ bias,
                                                 float* __restrict__ C) {
    __shared__ float As[64][17];
    __shared__ float Bs[64][17];
    int t = threadIdx.x;
    int tx = t & 15, ty = t >> 4;
    int m0 = blockIdx.y * 64, n0 = blockIdx.x * 64;
    float acc[4][4] = {};
    for (int k0 = 0; k0 < E_; k0 += 16) {
        #pragma unroll
        for (int i = 0; i < 4; ++i) {
            int r = (t >> 4) + i * 16, c = t & 15;
            As[r][c] = A[(size_t)(m0 + r) * E_ + k0 + c];
            Bs[r][c] = W[(size_t)(n0 + r) * E_ + k0 + c];
        }
        __syncthreads();
        #pragma unroll
        for (int k = 0; k < 16; ++k) {
            float a[4], b[4];
            #pragma unroll
            for (int i = 0; i < 4; ++i) a[i] = As[ty * 4 + i][k];
            #pragma unroll
            for (int j = 0; j < 4; ++j) b[j] = Bs[tx * 4 + j][k];
            #pragma unroll
            for (int i = 0; i < 4; ++i)
                #pragma unroll
                for (int j = 0; j < 4; ++j) acc[i][j] += a[i] * b[j];
        }
        __syncthreads();
    }
    #pragma unroll
    for (int i = 0; i < 4; ++i)
        #pragma unroll
        for (int j = 0; j < 4; ++j) {
            int m = m0 + ty * 4 + i, n = n0 + tx * 4 + j;
            C[(size_t)m * DC_ + n] = acc[i][j] + bias[n];
        }
}

// ---- score GEMM (NT) + exp epilogue: P[m][n] = exp(-X[m].CB[n]*rX[m]*rW[n]) (bf16),
//      Z[m] += row sums.  M=1024, N=16384, K=768.
__global__ __launch_bounds__(256) void score_gemm(const float* __restrict__ X,
                                                  const float* __restrict__ CB,
                                                  const float* __restrict__ rX,
                                                  const float* __restrict__ rW,
                                                  __hip_bfloat16* __restrict__ P,
                                                  float* __restrict__ Z) {
    __shared__ float As[64][17];
    __shared__ float Bs[64][17];
    int t = threadIdx.x;
    int tx = t & 15, ty = t >> 4;
    int m0 = blockIdx.y * 64, n0 = blockIdx.x * 64;
    float acc[4][4] = {};
    for (int k0 = 0; k0 < DC_; k0 += 16) {
        #pragma unroll
        for (int i = 0; i < 4; ++i) {
            int r = (t >> 4) + i * 16, c = t & 15;
            As[r][c] = X[(size_t)(m0 + r) * DC_ + k0 + c];
            Bs[r][c] = CB[(size_t)(n0 + r) * DC_ + k0 + c];
        }
        __syncthreads();
        #pragma unroll
        for (int k = 0; k < 16; ++k) {
            float a[4], b[4];
            #pragma unroll
            for (int i = 0; i < 4; ++i) a[i] = As[ty * 4 + i][k];
            #pragma unroll
            for (int j = 0; j < 4; ++j) b[j] = Bs[tx * 4 + j][k];
            #pragma unroll
            for (int i = 0; i < 4; ++i)
                #pragma unroll
                for (int j = 0; j < 4; ++j) acc[i][j] += a[i] * b[j];
        }
        __syncthreads();
    }
    float rx[4], rw[4];
    #pragma unroll
    for (int i = 0; i < 4; ++i) rx[i] = rX[m0 + ty * 4 + i];
    #pragma unroll
    for (int j = 0; j < 4; ++j) rw[j] = rW[n0 + tx * 4 + j];
    float rowsum[4] = {};
    #pragma unroll
    for (int i = 0; i < 4; ++i)
        #pragma unroll
        for (int j = 0; j < 4; ++j) {
            float e = __expf(-acc[i][j] * rx[i] * rw[j]);
            int m = m0 + ty * 4 + i, n = n0 + tx * 4 + j;
            P[(size_t)m * N_ + n] = __float2bfloat16(e);
            rowsum[i] += e;
        }
    // reduce row sums across tx into Z (reuse As)
    #pragma unroll
    for (int i = 0; i < 4; ++i) As[ty * 4 + i][tx] = rowsum[i];
    __syncthreads();
    if (t < 64) {
        float s = 0.0f;
        #pragma unroll
        for (int x = 0; x < 16; ++x) s += As[t][x];
        atomicAdd(&Z[m0 + t], s);
    }
}

// ---- output GEMM (NN, K-split): clue[m][d] += sum_k P[m][k]*CB[k][d] ----
// M=1024, N=768, K=16384 split into 4 chunks of 4096.
__global__ __launch_bounds__(256) void out_gemm(const __hip_bfloat16* __restrict__ P,
                                                const float* __restrict__ CB,
                                                float* __restrict__ clue) {
    __shared__ float Ps[64][17];
    __shared__ float Ws[16][65];
    int t = threadIdx.x;
    int tx = t & 15, ty = t >> 4;
    int m0 = blockIdx.y * 64, n0 = blockIdx.x * 64;
    int kbeg = blockIdx.z * (N_ / 4), kend = kbeg + N_ / 4;
    float acc[4][4] = {};
    for (int k0 = kbeg; k0 < kend; k0 += 16) {
        #pragma unroll
        for (int i = 0; i < 4; ++i) {
            int r = (t >> 4) + i * 16, c = t & 15;
            Ps[r][c] = __bfloat162float(P[(size_t)(m0 + r) * N_ + k0 + c]);
        }
        #pragma unroll
        for (int i = 0; i < 4; ++i) {
            int kk = (t >> 6) + i * 4, d = t & 63;
            Ws[kk][d] = CB[(size_t)(k0 + kk) * DC_ + n0 + d];
        }
        __syncthreads();
        #pragma unroll
        for (int k = 0; k < 16; ++k) {
            float a[4], b[4];
            #pragma unroll
            for (int i = 0; i < 4; ++i) a[i] = Ps[ty * 4 + i][k];
            #pragma unroll
            for (int j = 0; j < 4; ++j) b[j] = Ws[k][tx * 4 + j];
            #pragma unroll
            for (int i = 0; i < 4; ++i)
                #pragma unroll
                for (int j = 0; j < 4; ++j) acc[i][j] += a[i] * b[j];
        }
        __syncthreads();
    }
    #pragma unroll
    for (int i = 0; i < 4; ++i)
        #pragma unroll
        for (int j = 0; j < 4; ++j)
            atomicAdd(&clue[(size_t)(m0 + ty * 4 + i) * DC_ + n0 + tx * 4 + j], acc[i][j]);
}

// ---- assemble new_text_emb (float4 copy with row substitution) ----
__global__ __launch_bounds__(256) void assemble(const float* __restrict__ text,
                                                const float* __restrict__ clue,
                                                const float* __restrict__ Z,
                                                const int* __restrict__ vl,
                                                float* __restrict__ out) {
    int idx = blockIdx.x * 256 + threadIdx.x;      // float4 index, total 12,582,912
    int c = idx % 192;                              // float4 within a 768-row
    int bl = idx / 192;
    int l = bl & 63, b = bl >> 6;
    int v = vl[b];
    float4 val;
    if (l == v) {
        val = ((const float4*)text)[(size_t)(b * 64 + v - 1) * 192 + c];
    } else if (l == v - 1) {
        float invZ = 1.0f / Z[b];
        float4 t4 = ((const float4*)(clue + (size_t)b * DC_))[c];
        val = make_float4(t4.x * invZ, t4.y * invZ, t4.z * invZ, t4.w * invZ);
    } else {
        val = ((const float4*)text)[idx];
    }
    ((float4*)out)[idx] = val;
}

// ---- mask output (float 0/1) + scalar 0 ----
__global__ void mask_scalar(const int* __restrict__ vl, float* __restrict__ out_mask,
                            float* __restrict__ out_scalar) {
    int idx = blockIdx.x * blockDim.x + threadIdx.x;
    if (idx < B_ * L_) {
        int b = idx >> 6, j = idx & 63;
        out_mask[idx] = (j > vl[b]) ? 1.0f : 0.0f;
    }
    if (idx == 0) *out_scalar = 0.0f;
}

extern "C" void kernel_launch(void* const* d_in, const int* in_sizes, int n_in,
                              void* d_out, int out_size, void* d_ws, size_t ws_size,
                              hipStream_t stream) {
    const float* inputs  = (const float*)d_in[0];
    const float* text    = (const float*)d_in[1];
    const void*  mask    = d_in[2];
    const float* proj_w  = (const float*)d_in[3];
    const float* proj_b  = (const float*)d_in[4];
    const float* codebook= (const float*)d_in[5];
    float* out = (float*)d_out;

    char* ws = (char*)d_ws;
    float*          X    = (float*)(ws + 0);
    float*          clue = (float*)(ws + 3145728);
    __hip_bfloat16* P    = (__hip_bfloat16*)(ws + 6291456);
    float*          rX   = (float*)(ws + 39845888);
    float*          rW   = (float*)(ws + 39849984);
    float*          Z    = (float*)(ws + 39915520);
    int*            vl   = (int*)(ws + 39919616);
    int*            flag = (int*)(ws + 39923712);

    hipMemsetAsync(Z, 0, B_ * sizeof(float), stream);
    hipMemsetAsync(clue, 0, (size_t)B_ * DC_ * sizeof(float), stream);

    detect_mask<<<1, 256, 0, stream>>>((const unsigned int*)mask, flag);
    compute_vl<<<4, 256, 0, stream>>>(mask, flag, vl);
    rownorm<<<N_, 256, 0, stream>>>(codebook, rW, DC_);
    proj_gemm<<<dim3(DC_ / 64, B_ / 64), 256, 0, stream>>>(inputs, proj_w, proj_b, X);
    rownorm<<<B_, 256, 0, stream>>>(X, rX, DC_);
    score_gemm<<<dim3(N_ / 64, B_ / 64), 256, 0, stream>>>(X, codebook, rX, rW, P, Z);
    out_gemm<<<dim3(DC_ / 64, B_ / 64, 4), 256, 0, stream>>>(P, codebook, clue);
    assemble<<<49152, 256, 0, stream>>>(text, clue, Z, vl, out);
    mask_scalar<<<(B_ * L_ + 255) / 256, 256, 0, stream>>>(
        vl, out + (size_t)B_ * L_ * DC_, out + (size_t)B_ * L_ * DC_ + B_ * L_);
}

// Round 5
// 642.530 us; speedup vs baseline: 2.3883x; 2.3883x over previous
//
#include <hip/hip_runtime.h>
#include <hip/hip_bf16.h>

#define B_  1024
#define L_  64
#define E_  1024
#define DC_ 768
#define N_  16384

typedef short bf16x8 __attribute__((ext_vector_type(8)));
typedef float f32x4  __attribute__((ext_vector_type(4)));

// ---------------- ws layout (bytes) ----------------
// Xb   : 0            1024*768*2   = 1,572,864   bf16 projected x
// CBb  : 1572864      16384*768*2  = 25,165,824  bf16 codebook [n][k]
// CBt  : 26738688     768*16384*2  = 25,165,824  bf16 codebook^T [d][n]
// P    : 51904512     1024*16384*2 = 33,554,432  bf16 exp(-cos)
// clue : 85458944     1024*768*4   = 3,145,728   fp32 (atomic accum)
// rX   : 88604672     1024*4
// rW   : 88608768     16384*4
// Z    : 88674304     1024*4
// vl   : 88678400     1024*4
// flag : 88682496     4
// total ~88.7 MB

// ---- mask layout detection: 1 = int32 0/1, 2 = float32 0/1, 0 = bytes ----
__global__ void detect_mask(const unsigned int* __restrict__ mi, int* __restrict__ flag) {
    __shared__ int notInt, notFlt;
    if (threadIdx.x == 0) { notInt = 0; notFlt = 0; }
    __syncthreads();
    int ni = 0, nf = 0;
    for (int i = threadIdx.x; i < 16384; i += 256) {
        unsigned v = mi[i];
        if (v > 1u) ni = 1;
        if (v != 0u && v != 0x3f800000u) nf = 1;
    }
    if (ni) notInt = 1;
    if (nf) notFlt = 1;
    __syncthreads();
    if (threadIdx.x == 0) *flag = (!notInt) ? 1 : ((!notFlt) ? 2 : 0);
}

__global__ void compute_vl(const void* __restrict__ mask, const int* __restrict__ flag,
                           int* __restrict__ vl) {
    int b = blockIdx.x * blockDim.x + threadIdx.x;
    if (b >= B_) return;
    int f = *flag;
    int s = 0;
    if (f == 1) {
        const int* m = (const int*)mask;
        for (int j = 0; j < L_; ++j) s += m[b * L_ + j];
    } else if (f == 2) {
        const float* m = (const float*)mask;
        for (int j = 0; j < L_; ++j) s += (m[b * L_ + j] != 0.0f) ? 1 : 0;
    } else {
        const unsigned char* m = (const unsigned char*)mask;
        for (int j = 0; j < L_; ++j) s += m[b * L_ + j];
    }
    vl[b] = L_ - s;
}

// ---- row inverse-norm (fp32 source) ----
__global__ __launch_bounds__(256) void rownorm(const float* __restrict__ M,
                                               float* __restrict__ r, int cols) {
    int row = blockIdx.x;
    const float* p = M + (size_t)row * cols;
    float s = 0.0f;
    for (int c = threadIdx.x; c < cols; c += 256) { float v = p[c]; s += v * v; }
    for (int off = 32; off > 0; off >>= 1) s += __shfl_down(s, off);
    __shared__ float sm[4];
    if ((threadIdx.x & 63) == 0) sm[threadIdx.x >> 6] = s;
    __syncthreads();
    if (threadIdx.x == 0) {
        float t = sm[0] + sm[1] + sm[2] + sm[3];
        r[row] = 1.0f / fmaxf(sqrtf(t), 1e-8f);
    }
}

// ---- row inverse-norm (bf16 source) ----
__global__ __launch_bounds__(256) void rownorm_bf16(const __hip_bfloat16* __restrict__ M,
                                                    float* __restrict__ r, int cols) {
    int row = blockIdx.x;
    const __hip_bfloat16* p = M + (size_t)row * cols;
    float s = 0.0f;
    for (int c = threadIdx.x; c < cols; c += 256) { float v = __bfloat162float(p[c]); s += v * v; }
    for (int off = 32; off > 0; off >>= 1) s += __shfl_down(s, off);
    __shared__ float sm[4];
    if ((threadIdx.x & 63) == 0) sm[threadIdx.x >> 6] = s;
    __syncthreads();
    if (threadIdx.x == 0) {
        float t = sm[0] + sm[1] + sm[2] + sm[3];
        r[row] = 1.0f / fmaxf(sqrtf(t), 1e-8f);
    }
}

// ---- codebook prep: CBb = bf16(CB) [n][k]; CBt = bf16(CB)^T [d][n] ----
__global__ __launch_bounds__(256) void prep_cb(const float* __restrict__ CB,
                                               __hip_bfloat16* __restrict__ CBb,
                                               __hip_bfloat16* __restrict__ CBt) {
    __shared__ float t[64][65];
    int n0 = blockIdx.x * 64, d0 = blockIdx.y * 64;
    int tid = threadIdx.x;
    #pragma unroll
    for (int i = 0; i < 16; ++i) {
        int r = (tid >> 6) + i * 4, c = tid & 63;
        float v = CB[(size_t)(n0 + r) * DC_ + d0 + c];
        t[r][c] = v;
        CBb[(size_t)(n0 + r) * DC_ + d0 + c] = __float2bfloat16(v);
    }
    __syncthreads();
    #pragma unroll
    for (int i = 0; i < 16; ++i) {
        int r = (tid >> 6) + i * 4, c = tid & 63;
        CBt[(size_t)(d0 + r) * N_ + n0 + c] = __float2bfloat16(t[c][r]);
    }
}

// ---- proj GEMM (NT, fp32): Xb[m][n] = bf16( inputs[m]·proj_w[n] + b[n] ) ----
__global__ __launch_bounds__(256) void proj_gemm(const float* __restrict__ A,
                                                 const float* __restrict__ W,
                                                 const float* __restrict__ bias,
                                                 __hip_bfloat16* __restrict__ Xb) {
    __shared__ float As[64][17];
    __shared__ float Bs[64][17];
    int t = threadIdx.x;
    int tx = t & 15, ty = t >> 4;
    int m0 = blockIdx.y * 64, n0 = blockIdx.x * 64;
    float acc[4][4] = {};
    for (int k0 = 0; k0 < E_; k0 += 16) {
        #pragma unroll
        for (int i = 0; i < 4; ++i) {
            int r = (t >> 4) + i * 16, c = t & 15;
            As[r][c] = A[(size_t)(m0 + r) * E_ + k0 + c];
            Bs[r][c] = W[(size_t)(n0 + r) * E_ + k0 + c];
        }
        __syncthreads();
        #pragma unroll
        for (int k = 0; k < 16; ++k) {
            float a[4], b[4];
            #pragma unroll
            for (int i = 0; i < 4; ++i) a[i] = As[ty * 4 + i][k];
            #pragma unroll
            for (int j = 0; j < 4; ++j) b[j] = Bs[tx * 4 + j][k];
            #pragma unroll
            for (int i = 0; i < 4; ++i)
                #pragma unroll
                for (int j = 0; j < 4; ++j) acc[i][j] += a[i] * b[j];
        }
        __syncthreads();
    }
    #pragma unroll
    for (int i = 0; i < 4; ++i)
        #pragma unroll
        for (int j = 0; j < 4; ++j) {
            int m = m0 + ty * 4 + i, n = n0 + tx * 4 + j;
            Xb[(size_t)m * DC_ + n] = __float2bfloat16(acc[i][j] + bias[n]);
        }
}

// ======== MFMA NT GEMM machinery (128x128 tile, 4 waves 2x2, BK=32) ========
// LDS layout [128 rows][4 slots of 8 bf16], slot XOR-swizzled by (row&3).
// global_load_lds writes linearly (lane -> base + lane*16); the source address
// is inverse-swizzled so that LDS slot s of row r holds global slot s^(r&3).
__device__ __forceinline__ void stage_tile(const __hip_bfloat16* __restrict__ src, size_t ldk,
                                           __hip_bfloat16* smem, int wave, int lane) {
    #pragma unroll
    for (int s = 0; s < 2; ++s) {
        const int chunk = wave * 32 + s * 16;
        const int r = chunk + (lane >> 2);
        const int gslot = (lane & 3) ^ ((lane >> 2) & 3);
        const __hip_bfloat16* g = src + (size_t)r * ldk + gslot * 8;
        __builtin_amdgcn_global_load_lds(
            (const __attribute__((address_space(1))) void*)g,
            (__attribute__((address_space(3))) void*)(smem + chunk * 32), 16, 0, 0);
    }
}

__device__ __forceinline__ bf16x8 read_frag(const __hip_bfloat16* smem, int base_row, int lane) {
    const int r = base_row + (lane & 15);
    const int slot = ((lane >> 4) ^ r) & 3;
    return *(const bf16x8*)(smem + r * 32 + slot * 8);
}

// ---- score: P[m][n] = bf16(exp(-(Xb[m]·CBb[n])*rX[m]*rW[n])), Z[m] += rowsum ----
__global__ __launch_bounds__(256) void score_mfma(const __hip_bfloat16* __restrict__ Xb,
                                                  const __hip_bfloat16* __restrict__ CBb,
                                                  const float* __restrict__ rX,
                                                  const float* __restrict__ rW,
                                                  __hip_bfloat16* __restrict__ P,
                                                  float* __restrict__ Z) {
    __shared__ __align__(16) __hip_bfloat16 As[128 * 32];
    __shared__ __align__(16) __hip_bfloat16 Bs[128 * 32];
    const int t = threadIdx.x, lane = t & 63, wave = t >> 6;
    const int wr = wave >> 1, wc = wave & 1;
    const int m0 = blockIdx.y * 128, n0 = blockIdx.x * 128;

    f32x4 acc[4][4];
    #pragma unroll
    for (int i = 0; i < 4; ++i)
        #pragma unroll
        for (int j = 0; j < 4; ++j) acc[i][j] = (f32x4){0.f, 0.f, 0.f, 0.f};

    const __hip_bfloat16* Asrc = Xb  + (size_t)m0 * DC_;
    const __hip_bfloat16* Bsrc = CBb + (size_t)n0 * DC_;
    for (int k0 = 0; k0 < DC_; k0 += 32) {
        stage_tile(Asrc + k0, DC_, As, wave, lane);
        stage_tile(Bsrc + k0, DC_, Bs, wave, lane);
        __syncthreads();
        bf16x8 af[4], bg[4];
        #pragma unroll
        for (int i = 0; i < 4; ++i) af[i] = read_frag(As, wr * 64 + i * 16, lane);
        #pragma unroll
        for (int j = 0; j < 4; ++j) bg[j] = read_frag(Bs, wc * 64 + j * 16, lane);
        #pragma unroll
        for (int i = 0; i < 4; ++i)
            #pragma unroll
            for (int j = 0; j < 4; ++j)
                acc[i][j] = __builtin_amdgcn_mfma_f32_16x16x32_bf16(af[i], bg[j], acc[i][j], 0, 0, 0);
        __syncthreads();
    }

    const int fr = lane & 15, fq = lane >> 4;
    float rw[4];
    #pragma unroll
    for (int j = 0; j < 4; ++j) rw[j] = rW[n0 + wc * 64 + j * 16 + fr];
    #pragma unroll
    for (int i = 0; i < 4; ++i) {
        const int mb = m0 + wr * 64 + i * 16 + fq * 4;
        float rx[4];
        #pragma unroll
        for (int q = 0; q < 4; ++q) rx[q] = rX[mb + q];
        float rs[4] = {0.f, 0.f, 0.f, 0.f};
        #pragma unroll
        for (int j = 0; j < 4; ++j) {
            const int n = n0 + wc * 64 + j * 16 + fr;
            #pragma unroll
            for (int q = 0; q < 4; ++q) {
                float e = __expf(-acc[i][j][q] * rx[q] * rw[j]);
                P[(size_t)(mb + q) * N_ + n] = __float2bfloat16(e);
                rs[q] += e;
            }
        }
        #pragma unroll
        for (int q = 0; q < 4; ++q) {
            float s = rs[q];
            s += __shfl_xor(s, 1); s += __shfl_xor(s, 2);
            s += __shfl_xor(s, 4); s += __shfl_xor(s, 8);
            if (fr == 0) atomicAdd(&Z[mb + q], s);
        }
    }
}

// ---- readout: clue[m][d] += sum_n P[m][n]*CBt[d][n]  (K split x8, atomic) ----
__global__ __launch_bounds__(256) void out_mfma(const __hip_bfloat16* __restrict__ P,
                                                const __hip_bfloat16* __restrict__ CBt,
                                                float* __restrict__ clue) {
    __shared__ __align__(16) __hip_bfloat16 As[128 * 32];
    __shared__ __align__(16) __hip_bfloat16 Bs[128 * 32];
    const int t = threadIdx.x, lane = t & 63, wave = t >> 6;
    const int wr = wave >> 1, wc = wave & 1;
    const int m0 = blockIdx.y * 128, d0 = blockIdx.x * 128;
    const int kbeg = blockIdx.z * (N_ / 8);

    f32x4 acc[4][4];
    #pragma unroll
    for (int i = 0; i < 4; ++i)
        #pragma unroll
        for (int j = 0; j < 4; ++j) acc[i][j] = (f32x4){0.f, 0.f, 0.f, 0.f};

    const __hip_bfloat16* Asrc = P   + (size_t)m0 * N_;
    const __hip_bfloat16* Bsrc = CBt + (size_t)d0 * N_;
    for (int kk = 0; kk < N_ / 8; kk += 32) {
        const int k0 = kbeg + kk;
        stage_tile(Asrc + k0, N_, As, wave, lane);
        stage_tile(Bsrc + k0, N_, Bs, wave, lane);
        __syncthreads();
        bf16x8 af[4], bg[4];
        #pragma unroll
        for (int i = 0; i < 4; ++i) af[i] = read_frag(As, wr * 64 + i * 16, lane);
        #pragma unroll
        for (int j = 0; j < 4; ++j) bg[j] = read_frag(Bs, wc * 64 + j * 16, lane);
        #pragma unroll
        for (int i = 0; i < 4; ++i)
            #pragma unroll
            for (int j = 0; j < 4; ++j)
                acc[i][j] = __builtin_amdgcn_mfma_f32_16x16x32_bf16(af[i], bg[j], acc[i][j], 0, 0, 0);
        __syncthreads();
    }

    const int fr = lane & 15, fq = lane >> 4;
    #pragma unroll
    for (int i = 0; i < 4; ++i) {
        const int mb = m0 + wr * 64 + i * 16 + fq * 4;
        #pragma unroll
        for (int j = 0; j < 4; ++j) {
            const int d = d0 + wc * 64 + j * 16 + fr;
            #pragma unroll
            for (int q = 0; q < 4; ++q)
                atomicAdd(&clue[(size_t)(mb + q) * DC_ + d], acc[i][j][q]);
        }
    }
}

// ---- assemble new_text_emb (float4 copy with row substitution) ----
__global__ __launch_bounds__(256) void assemble(const float* __restrict__ text,
                                                const float* __restrict__ clue,
                                                const float* __restrict__ Z,
                                                const int* __restrict__ vl,
                                                float* __restrict__ out) {
    int idx = blockIdx.x * 256 + threadIdx.x;      // float4 index
    int c = idx % 192;
    int bl = idx / 192;
    int l = bl & 63, b = bl >> 6;
    int v = vl[b];
    float4 val;
    if (l == v) {
        val = ((const float4*)text)[(size_t)(b * 64 + v - 1) * 192 + c];
    } else if (l == v - 1) {
        float invZ = 1.0f / Z[b];
        float4 t4 = ((const float4*)(clue + (size_t)b * DC_))[c];
        val = make_float4(t4.x * invZ, t4.y * invZ, t4.z * invZ, t4.w * invZ);
    } else {
        val = ((const float4*)text)[idx];
    }
    ((float4*)out)[idx] = val;
}

// ---- mask output (float 0/1) + scalar 0 ----
__global__ void mask_scalar(const int* __restrict__ vl, float* __restrict__ out_mask,
                            float* __restrict__ out_scalar) {
    int idx = blockIdx.x * blockDim.x + threadIdx.x;
    if (idx < B_ * L_) {
        int b = idx >> 6, j = idx & 63;
        out_mask[idx] = (j > vl[b]) ? 1.0f : 0.0f;
    }
    if (idx == 0) *out_scalar = 0.0f;
}

extern "C" void kernel_launch(void* const* d_in, const int* in_sizes, int n_in,
                              void* d_out, int out_size, void* d_ws, size_t ws_size,
                              hipStream_t stream) {
    const float* inputs  = (const float*)d_in[0];
    const float* text    = (const float*)d_in[1];
    const void*  mask    = d_in[2];
    const float* proj_w  = (const float*)d_in[3];
    const float* proj_b  = (const float*)d_in[4];
    const float* codebook= (const float*)d_in[5];
    float* out = (float*)d_out;

    char* ws = (char*)d_ws;
    __hip_bfloat16* Xb   = (__hip_bfloat16*)(ws + 0);
    __hip_bfloat16* CBb  = (__hip_bfloat16*)(ws + 1572864);
    __hip_bfloat16* CBt  = (__hip_bfloat16*)(ws + 26738688);
    __hip_bfloat16* P    = (__hip_bfloat16*)(ws + 51904512);
    float*          clue = (float*)(ws + 85458944);
    float*          rX   = (float*)(ws + 88604672);
    float*          rW   = (float*)(ws + 88608768);
    float*          Z    = (float*)(ws + 88674304);
    int*            vl   = (int*)(ws + 88678400);
    int*            flag = (int*)(ws + 88682496);

    hipMemsetAsync(Z, 0, B_ * sizeof(float), stream);
    hipMemsetAsync(clue, 0, (size_t)B_ * DC_ * sizeof(float), stream);

    detect_mask<<<1, 256, 0, stream>>>((const unsigned int*)mask, flag);
    compute_vl<<<4, 256, 0, stream>>>(mask, flag, vl);
    rownorm<<<N_, 256, 0, stream>>>(codebook, rW, DC_);
    prep_cb<<<dim3(N_ / 64, DC_ / 64), 256, 0, stream>>>(codebook, CBb, CBt);
    proj_gemm<<<dim3(DC_ / 64, B_ / 64), 256, 0, stream>>>(inputs, proj_w, proj_b, Xb);
    rownorm_bf16<<<B_, 256, 0, stream>>>(Xb, rX, DC_);
    score_mfma<<<dim3(N_ / 128, B_ / 128), 256, 0, stream>>>(Xb, CBb, rX, rW, P, Z);
    out_mfma<<<dim3(DC_ / 128, B_ / 128, 8), 256, 0, stream>>>(P, CBt, clue);
    assemble<<<49152, 256, 0, stream>>>(text, clue, Z, vl, out);
    mask_scalar<<<(B_ * L_ + 255) / 256, 256, 0, stream>>>(
        vl, out + (size_t)B_ * L_ * DC_, out + (size_t)B_ * L_ * DC_ + B_ * L_);
}

// Round 8
// 594.753 us; speedup vs baseline: 2.5802x; 1.0803x over previous
//
#include <hip/hip_runtime.h>
#include <hip/hip_bf16.h>

#define B_  1024
#define L_  64
#define E_  1024
#define DC_ 768
#define N_  16384
#define NZ_ 16                      // K-split slices for readout GEMM

typedef short bf16x8 __attribute__((ext_vector_type(8)));
typedef float f32x4  __attribute__((ext_vector_type(4)));

// ---------------- ws layout (bytes) ----------------
// Xb       : 0          1024*768*2            = 1,572,864
// CBb      : 1572864    16384*768*2           = 25,165,824
// CBt      : 26738688   768*16384*2           = 25,165,824
// P        : 51904512   1024*16384*2          = 33,554,432
//   inb    : 51904512   (overlaps P) 1024*1024*2 = 2,097,152   dead before P written
//   pwb    : 54001664   (overlaps P) 768*1024*2  = 1,572,864
// cluePart : 85458944   16*1024*768*4         = 50,331,648
// clueF    : 135790592  1024*768*4            = 3,145,728
// rX       : 138936320  4096
// rW       : 138940416  65536
// Z        : 139005952  4096
// vl       : 139010048  4096
// flag     : 139014144  4
// total ~139 MB (ws evidenced ~800 MB by harness poison fills)

// ---- mask layout detection: 1 = int32 0/1, 2 = float32 0/1, 0 = bytes ----
__global__ void detect_mask(const unsigned int* __restrict__ mi, int* __restrict__ flag) {
    __shared__ int notInt, notFlt;
    if (threadIdx.x == 0) { notInt = 0; notFlt = 0; }
    __syncthreads();
    int ni = 0, nf = 0;
    for (int i = threadIdx.x; i < 16384; i += 256) {
        unsigned v = mi[i];
        if (v > 1u) ni = 1;
        if (v != 0u && v != 0x3f800000u) nf = 1;
    }
    if (ni) notInt = 1;
    if (nf) notFlt = 1;
    __syncthreads();
    if (threadIdx.x == 0) *flag = (!notInt) ? 1 : ((!notFlt) ? 2 : 0);
}

__global__ void compute_vl(const void* __restrict__ mask, const int* __restrict__ flag,
                           int* __restrict__ vl) {
    int b = blockIdx.x * blockDim.x + threadIdx.x;
    if (b >= B_) return;
    int f = *flag;
    int s = 0;
    if (f == 1) {
        const int* m = (const int*)mask;
        for (int j = 0; j < L_; ++j) s += m[b * L_ + j];
    } else if (f == 2) {
        const float* m = (const float*)mask;
        for (int j = 0; j < L_; ++j) s += (m[b * L_ + j] != 0.0f) ? 1 : 0;
    } else {
        const unsigned char* m = (const unsigned char*)mask;
        for (int j = 0; j < L_; ++j) s += m[b * L_ + j];
    }
    vl[b] = L_ - s;
}

// ---- row inverse-norm (fp32 source) ----
__global__ __launch_bounds__(256) void rownorm(const float* __restrict__ M,
                                               float* __restrict__ r, int cols) {
    int row = blockIdx.x;
    const float* p = M + (size_t)row * cols;
    float s = 0.0f;
    for (int c = threadIdx.x; c < cols; c += 256) { float v = p[c]; s += v * v; }
    for (int off = 32; off > 0; off >>= 1) s += __shfl_down(s, off);
    __shared__ float sm[4];
    if ((threadIdx.x & 63) == 0) sm[threadIdx.x >> 6] = s;
    __syncthreads();
    if (threadIdx.x == 0) {
        float t = sm[0] + sm[1] + sm[2] + sm[3];
        r[row] = 1.0f / fmaxf(sqrtf(t), 1e-8f);
    }
}

// ---- row inverse-norm (bf16 source) ----
__global__ __launch_bounds__(256) void rownorm_bf16(const __hip_bfloat16* __restrict__ M,
                                                    float* __restrict__ r, int cols) {
    int row = blockIdx.x;
    const __hip_bfloat16* p = M + (size_t)row * cols;
    float s = 0.0f;
    for (int c = threadIdx.x; c < cols; c += 256) { float v = __bfloat162float(p[c]); s += v * v; }
    for (int off = 32; off > 0; off >>= 1) s += __shfl_down(s, off);
    __shared__ float sm[4];
    if ((threadIdx.x & 63) == 0) sm[threadIdx.x >> 6] = s;
    __syncthreads();
    if (threadIdx.x == 0) {
        float t = sm[0] + sm[1] + sm[2] + sm[3];
        r[row] = 1.0f / fmaxf(sqrtf(t), 1e-8f);
    }
}

// ---- codebook prep: CBb = bf16(CB) [n][k]; CBt = bf16(CB)^T [d][n] ----
__global__ __launch_bounds__(256) void prep_cb(const float* __restrict__ CB,
                                               __hip_bfloat16* __restrict__ CBb,
                                               __hip_bfloat16* __restrict__ CBt) {
    __shared__ float t[64][65];
    int n0 = blockIdx.x * 64, d0 = blockIdx.y * 64;
    int tid = threadIdx.x;
    #pragma unroll
    for (int i = 0; i < 16; ++i) {
        int r = (tid >> 6) + i * 4, c = tid & 63;
        float v = CB[(size_t)(n0 + r) * DC_ + d0 + c];
        t[r][c] = v;
        CBb[(size_t)(n0 + r) * DC_ + d0 + c] = __float2bfloat16(v);
    }
    __syncthreads();
    #pragma unroll
    for (int i = 0; i < 16; ++i) {
        int r = (tid >> 6) + i * 4, c = tid & 63;
        CBt[(size_t)(d0 + r) * N_ + n0 + c] = __float2bfloat16(t[c][r]);
    }
}

// ---- elementwise fp32 -> bf16 cast (vectorized), n divisible by 4 ----
__global__ __launch_bounds__(256) void cast_bf16(const float* __restrict__ src,
                                                 ushort* __restrict__ dst, int n4) {
    int idx = blockIdx.x * 256 + threadIdx.x;
    if (idx >= n4) return;
    float4 v = ((const float4*)src)[idx];
    ushort4 o;
    __hip_bfloat16 h0 = __float2bfloat16(v.x); o.x = __builtin_bit_cast(ushort, h0);
    __hip_bfloat16 h1 = __float2bfloat16(v.y); o.y = __builtin_bit_cast(ushort, h1);
    __hip_bfloat16 h2 = __float2bfloat16(v.z); o.z = __builtin_bit_cast(ushort, h2);
    __hip_bfloat16 h3 = __float2bfloat16(v.w); o.w = __builtin_bit_cast(ushort, h3);
    ((ushort4*)dst)[idx] = o;
}

// ======== MFMA NT GEMM machinery (128x128 tile, 4 waves 2x2, BK=32) ========
// LDS layout [128 rows][4 slots of 8 bf16], slot XOR-swizzled by (row&3).
// global_load_lds writes linearly (lane -> base + lane*16); the source address
// is inverse-swizzled so that LDS slot s of row r holds global slot s^(r&3).
// Validated (round 5: absmax 3.8e-6).
__device__ __forceinline__ void stage_tile(const __hip_bfloat16* __restrict__ src, size_t ldk,
                                           __hip_bfloat16* smem, int wave, int lane) {
    #pragma unroll
    for (int s = 0; s < 2; ++s) {
        const int chunk = wave * 32 + s * 16;
        const int r = chunk + (lane >> 2);
        const int gslot = (lane & 3) ^ ((lane >> 2) & 3);
        const __hip_bfloat16* g = src + (size_t)r * ldk + gslot * 8;
        __builtin_amdgcn_global_load_lds(
            (const __attribute__((address_space(1))) void*)g,
            (__attribute__((address_space(3))) void*)(smem + chunk * 32), 16, 0, 0);
    }
}

__device__ __forceinline__ bf16x8 read_frag(const __hip_bfloat16* smem, int base_row, int lane) {
    const int r = base_row + (lane & 15);
    const int slot = ((lane >> 4) ^ r) & 3;
    return *(const bf16x8*)(smem + r * 32 + slot * 8);
}

// ---- proj: Xb[m][d] = bf16( inb[m]·pwb[d] + bias[d] ), M=1024 N=768 K=1024 ----
__global__ __launch_bounds__(256) void proj_mfma(const __hip_bfloat16* __restrict__ inb,
                                                 const __hip_bfloat16* __restrict__ pwb,
                                                 const float* __restrict__ bias,
                                                 __hip_bfloat16* __restrict__ Xb) {
    __shared__ __align__(16) __hip_bfloat16 As[128 * 32];
    __shared__ __align__(16) __hip_bfloat16 Bs[128 * 32];
    const int t = threadIdx.x, lane = t & 63, wave = t >> 6;
    const int wr = wave >> 1, wc = wave & 1;
    const int m0 = blockIdx.y * 128, n0 = blockIdx.x * 128;

    f32x4 acc[4][4];
    #pragma unroll
    for (int i = 0; i < 4; ++i)
        #pragma unroll
        for (int j = 0; j < 4; ++j) acc[i][j] = (f32x4){0.f, 0.f, 0.f, 0.f};

    const __hip_bfloat16* Asrc = inb + (size_t)m0 * E_;
    const __hip_bfloat16* Bsrc = pwb + (size_t)n0 * E_;
    for (int k0 = 0; k0 < E_; k0 += 32) {
        stage_tile(Asrc + k0, E_, As, wave, lane);
        stage_tile(Bsrc + k0, E_, Bs, wave, lane);
        __syncthreads();
        bf16x8 af[4], bg[4];
        #pragma unroll
        for (int i = 0; i < 4; ++i) af[i] = read_frag(As, wr * 64 + i * 16, lane);
        #pragma unroll
        for (int j = 0; j < 4; ++j) bg[j] = read_frag(Bs, wc * 64 + j * 16, lane);
        #pragma unroll
        for (int i = 0; i < 4; ++i)
            #pragma unroll
            for (int j = 0; j < 4; ++j)
                acc[i][j] = __builtin_amdgcn_mfma_f32_16x16x32_bf16(af[i], bg[j], acc[i][j], 0, 0, 0);
        __syncthreads();
    }

    const int fr = lane & 15, fq = lane >> 4;
    #pragma unroll
    for (int i = 0; i < 4; ++i) {
        const int mb = m0 + wr * 64 + i * 16 + fq * 4;
        #pragma unroll
        for (int j = 0; j < 4; ++j) {
            const int d = n0 + wc * 64 + j * 16 + fr;
            const float bv = bias[d];
            #pragma unroll
            for (int q = 0; q < 4; ++q)
                Xb[(size_t)(mb + q) * DC_ + d] = __float2bfloat16(acc[i][j][q] + bv);
        }
    }
}

// ---- score: P[m][n] = bf16(exp(-(Xb[m]·CBb[n])*rX[m]*rW[n])), Z[m] += rowsum ----
__global__ __launch_bounds__(256) void score_mfma(const __hip_bfloat16* __restrict__ Xb,
                                                  const __hip_bfloat16* __restrict__ CBb,
                                                  const float* __restrict__ rX,
                                                  const float* __restrict__ rW,
                                                  __hip_bfloat16* __restrict__ P,
                                                  float* __restrict__ Z) {
    __shared__ __align__(16) __hip_bfloat16 As[128 * 32];
    __shared__ __align__(16) __hip_bfloat16 Bs[128 * 32];
    const int t = threadIdx.x, lane = t & 63, wave = t >> 6;
    const int wr = wave >> 1, wc = wave & 1;
    const int m0 = blockIdx.y * 128, n0 = blockIdx.x * 128;

    f32x4 acc[4][4];
    #pragma unroll
    for (int i = 0; i < 4; ++i)
        #pragma unroll
        for (int j = 0; j < 4; ++j) acc[i][j] = (f32x4){0.f, 0.f, 0.f, 0.f};

    const __hip_bfloat16* Asrc = Xb  + (size_t)m0 * DC_;
    const __hip_bfloat16* Bsrc = CBb + (size_t)n0 * DC_;
    for (int k0 = 0; k0 < DC_; k0 += 32) {
        stage_tile(Asrc + k0, DC_, As, wave, lane);
        stage_tile(Bsrc + k0, DC_, Bs, wave, lane);
        __syncthreads();
        bf16x8 af[4], bg[4];
        #pragma unroll
        for (int i = 0; i < 4; ++i) af[i] = read_frag(As, wr * 64 + i * 16, lane);
        #pragma unroll
        for (int j = 0; j < 4; ++j) bg[j] = read_frag(Bs, wc * 64 + j * 16, lane);
        #pragma unroll
        for (int i = 0; i < 4; ++i)
            #pragma unroll
            for (int j = 0; j < 4; ++j)
                acc[i][j] = __builtin_amdgcn_mfma_f32_16x16x32_bf16(af[i], bg[j], acc[i][j], 0, 0, 0);
        __syncthreads();
    }

    const int fr = lane & 15, fq = lane >> 4;
    float rw[4];
    #pragma unroll
    for (int j = 0; j < 4; ++j) rw[j] = rW[n0 + wc * 64 + j * 16 + fr];
    #pragma unroll
    for (int i = 0; i < 4; ++i) {
        const int mb = m0 + wr * 64 + i * 16 + fq * 4;
        float rx[4];
        #pragma unroll
        for (int q = 0; q < 4; ++q) rx[q] = rX[mb + q];
        float rs[4] = {0.f, 0.f, 0.f, 0.f};
        #pragma unroll
        for (int j = 0; j < 4; ++j) {
            const int n = n0 + wc * 64 + j * 16 + fr;
            #pragma unroll
            for (int q = 0; q < 4; ++q) {
                float e = __expf(-acc[i][j][q] * rx[q] * rw[j]);
                P[(size_t)(mb + q) * N_ + n] = __float2bfloat16(e);
                rs[q] += e;
            }
        }
        #pragma unroll
        for (int q = 0; q < 4; ++q) {
            float s = rs[q];
            s += __shfl_xor(s, 1); s += __shfl_xor(s, 2);
            s += __shfl_xor(s, 4); s += __shfl_xor(s, 8);
            if (fr == 0) atomicAdd(&Z[mb + q], s);
        }
    }
}

// ---- readout: cluePart[z][m][d] = sum_{n in slice z} P[m][n]*CBt[d][n] ----
// Plain stores (no atomics); NZ_=16 slices of K=1024 each.
__global__ __launch_bounds__(256) void out_mfma(const __hip_bfloat16* __restrict__ P,
                                                const __hip_bfloat16* __restrict__ CBt,
                                                float* __restrict__ cluePart) {
    __shared__ __align__(16) __hip_bfloat16 As[128 * 32];
    __shared__ __align__(16) __hip_bfloat16 Bs[128 * 32];
    const int t = threadIdx.x, lane = t & 63, wave = t >> 6;
    const int wr = wave >> 1, wc = wave & 1;
    const int m0 = blockIdx.y * 128, d0 = blockIdx.x * 128;
    const int kbeg = blockIdx.z * (N_ / NZ_);
    float* outp = cluePart + (size_t)blockIdx.z * (B_ * DC_);

    f32x4 acc[4][4];
    #pragma unroll
    for (int i = 0; i < 4; ++i)
        #pragma unroll
        for (int j = 0; j < 4; ++j) acc[i][j] = (f32x4){0.f, 0.f, 0.f, 0.f};

    const __hip_bfloat16* Asrc = P   + (size_t)m0 * N_;
    const __hip_bfloat16* Bsrc = CBt + (size_t)d0 * N_;
    for (int kk = 0; kk < N_ / NZ_; kk += 32) {
        const int k0 = kbeg + kk;
        stage_tile(Asrc + k0, N_, As, wave, lane);
        stage_tile(Bsrc + k0, N_, Bs, wave, lane);
        __syncthreads();
        bf16x8 af[4], bg[4];
        #pragma unroll
        for (int i = 0; i < 4; ++i) af[i] = read_frag(As, wr * 64 + i * 16, lane);
        #pragma unroll
        for (int j = 0; j < 4; ++j) bg[j] = read_frag(Bs, wc * 64 + j * 16, lane);
        #pragma unroll
        for (int i = 0; i < 4; ++i)
            #pragma unroll
            for (int j = 0; j < 4; ++j)
                acc[i][j] = __builtin_amdgcn_mfma_f32_16x16x32_bf16(af[i], bg[j], acc[i][j], 0, 0, 0);
        __syncthreads();
    }

    const int fr = lane & 15, fq = lane >> 4;
    #pragma unroll
    for (int i = 0; i < 4; ++i) {
        const int mb = m0 + wr * 64 + i * 16 + fq * 4;
        #pragma unroll
        for (int j = 0; j < 4; ++j) {
            const int d = d0 + wc * 64 + j * 16 + fr;
            #pragma unroll
            for (int q = 0; q < 4; ++q)
                outp[(size_t)(mb + q) * DC_ + d] = acc[i][j][q];
        }
    }
}

// ---- reduce partials + normalize: clueF[b][d] = (sum_z cluePart[z][b][d]) / Z[b] ----
__global__ __launch_bounds__(256) void reduce_clue(const float* __restrict__ cluePart,
                                                   const float* __restrict__ Z,
                                                   float* __restrict__ clueF) {
    const int d = blockIdx.x * 256 + threadIdx.x;   // 0..767 (grid.x = 3)
    const int b = blockIdx.y;
    float s = 0.0f;
    #pragma unroll
    for (int z = 0; z < NZ_; ++z)
        s += cluePart[(size_t)z * (B_ * DC_) + (size_t)b * DC_ + d];
    clueF[(size_t)b * DC_ + d] = s / Z[b];
}

// ---- assemble new_text_emb (float4 copy with row substitution) ----
__global__ __launch_bounds__(256) void assemble(const float* __restrict__ text,
                                                const float* __restrict__ clueF,
                                                const int* __restrict__ vl,
                                                float* __restrict__ out) {
    int idx = blockIdx.x * 256 + threadIdx.x;      // float4 index
    int c = idx % 192;
    int bl = idx / 192;
    int l = bl & 63, b = bl >> 6;
    int v = vl[b];
    float4 val;
    if (l == v) {
        val = ((const float4*)text)[(size_t)(b * 64 + v - 1) * 192 + c];
    } else if (l == v - 1) {
        val = ((const float4*)(clueF + (size_t)b * DC_))[c];
    } else {
        val = ((const float4*)text)[idx];
    }
    ((float4*)out)[idx] = val;
}

// ---- mask output (float 0/1) + scalar 0 ----
__global__ void mask_scalar(const int* __restrict__ vl, float* __restrict__ out_mask,
                            float* __restrict__ out_scalar) {
    int idx = blockIdx.x * blockDim.x + threadIdx.x;
    if (idx < B_ * L_) {
        int b = idx >> 6, j = idx & 63;
        out_mask[idx] = (j > vl[b]) ? 1.0f : 0.0f;
    }
    if (idx == 0) *out_scalar = 0.0f;
}

extern "C" void kernel_launch(void* const* d_in, const int* in_sizes, int n_in,
                              void* d_out, int out_size, void* d_ws, size_t ws_size,
                              hipStream_t stream) {
    const float* inputs  = (const float*)d_in[0];
    const float* text    = (const float*)d_in[1];
    const void*  mask    = d_in[2];
    const float* proj_w  = (const float*)d_in[3];
    const float* proj_b  = (const float*)d_in[4];
    const float* codebook= (const float*)d_in[5];
    float* out = (float*)d_out;

    char* ws = (char*)d_ws;
    __hip_bfloat16* Xb       = (__hip_bfloat16*)(ws + 0);
    __hip_bfloat16* CBb      = (__hip_bfloat16*)(ws + 1572864);
    __hip_bfloat16* CBt      = (__hip_bfloat16*)(ws + 26738688);
    __hip_bfloat16* P        = (__hip_bfloat16*)(ws + 51904512);
    __hip_bfloat16* inb      = (__hip_bfloat16*)(ws + 51904512);           // overlaps P
    __hip_bfloat16* pwb      = (__hip_bfloat16*)(ws + 54001664);           // overlaps P
    float*          cluePart = (float*)(ws + 85458944);
    float*          clueF    = (float*)(ws + 135790592);
    float*          rX       = (float*)(ws + 138936320);
    float*          rW       = (float*)(ws + 138940416);
    float*          Z        = (float*)(ws + 139005952);
    int*            vl       = (int*)(ws + 139010048);
    int*            flag     = (int*)(ws + 139014144);

    hipMemsetAsync(Z, 0, B_ * sizeof(float), stream);

    detect_mask<<<1, 256, 0, stream>>>((const unsigned int*)mask, flag);
    compute_vl<<<4, 256, 0, stream>>>(mask, flag, vl);
    rownorm<<<N_, 256, 0, stream>>>(codebook, rW, DC_);
    prep_cb<<<dim3(N_ / 64, DC_ / 64), 256, 0, stream>>>(codebook, CBb, CBt);
    cast_bf16<<<(B_ * E_ / 4 + 255) / 256, 256, 0, stream>>>(inputs, (ushort*)inb, B_ * E_ / 4);
    cast_bf16<<<(DC_ * E_ / 4 + 255) / 256, 256, 0, stream>>>(proj_w, (ushort*)pwb, DC_ * E_ / 4);
    proj_mfma<<<dim3(DC_ / 128, B_ / 128), 256, 0, stream>>>(inb, pwb, proj_b, Xb);
    rownorm_bf16<<<B_, 256, 0, stream>>>(Xb, rX, DC_);
    score_mfma<<<dim3(N_ / 128, B_ / 128), 256, 0, stream>>>(Xb, CBb, rX, rW, P, Z);
    out_mfma<<<dim3(DC_ / 128, B_ / 128, NZ_), 256, 0, stream>>>(P, CBt, cluePart);
    reduce_clue<<<dim3(DC_ / 256, B_), 256, 0, stream>>>(cluePart, Z, clueF);
    assemble<<<49152, 256, 0, stream>>>(text, clueF, vl, out);
    mask_scalar<<<(B_ * L_ + 255) / 256, 256, 0, stream>>>(
        vl, out + (size_t)B_ * L_ * DC_, out + (size_t)B_ * L_ * DC_ + B_ * L_);
}